// Round 11
// baseline (110.903 us; speedup 1.0000x reference)
//
#include <hip/hip_runtime.h>

#define BATCH   16
#define CLEN    2048
#define DHEAD   2048
#define NT      256
#define NROWS   (BATCH * CLEN)        // 32768 output rows
#define NPAIR   (NROWS / 2)           // 16384 row pairs
#define SMBLK   512                   // softmax blocks in combo kernel
#define SMWAVES (SMBLK * 4)           // 2048 softmax waves
#define PPW     (NPAIR / SMWAVES)     // 8 pairs per wave
#define SWGRID  1024                  // sweep blocks (2 blocks per half-row pair)
#define SWK     (NROWS / (SWGRID/2))  // 64 k-steps

typedef float f32x4 __attribute__((ext_vector_type(4)));

// ws layout (floats):
// [0..5]    : M00,M01,M10,M11,b2_0,b2_1
// [6..37]   : per-batch absmax mx[16][2]
// [40 ..]   : u0[2048], u1[2048], w[2048]   (quad-aligned: 40%4==0)
// [WS_PART] : prep partials [64 chunks][3][2048]
// [WS_S ..] : S coefficients [32768][2]
#define WS_MX   6
#define WS_U0   40
#define WS_U1   (40 + DHEAD)
#define WS_W    (40 + 2*DHEAD)
#define WS_PART (40 + 3*DHEAD)
#define WS_S    (WS_PART + 64*3*DHEAD)

// ---- prep B1 (+A fused): y<64: partial u chunks; y==64: M/b2 (x==0) or absmax (x>=1) ----
__global__ void prep_u_partial(const float* __restrict__ Wv, const float* __restrict__ bv,
                               const float* __restrict__ Wo, const float* __restrict__ Wq,
                               const float* __restrict__ Wk, const float* __restrict__ bq,
                               const float* __restrict__ x, float* __restrict__ ws) {
    const int t = threadIdx.x;
    if (blockIdx.y < 64) {
        int o  = blockIdx.x * NT + t;                // column of Wo, 0..2047
        int hb = blockIdx.y * 32;                    // 64 chunks of 32 rows
        float p0=0.f, p1=0.f, pw=0.f;
        #pragma unroll 4
        for (int h = hb; h < hb + 32; ++h) {
            float wo = Wo[(size_t)h * DHEAD + o];
            p0 += Wv[h]         * wo;
            p1 += Wv[DHEAD + h] * wo;
            pw += bv[h]         * wo;
        }
        float* part = ws + WS_PART;
        part[((size_t)blockIdx.y*3 + 0)*DHEAD + o] = p0;
        part[((size_t)blockIdx.y*3 + 1)*DHEAD + o] = p1;
        part[((size_t)blockIdx.y*3 + 2)*DHEAD + o] = pw;
    } else if (blockIdx.x == 0) {
        // M = Wq Wk^T (2x2), b2 = Wk @ bq
        __shared__ float red[NT][6];
        float m00=0.f,m01=0.f,m10=0.f,m11=0.f,b20=0.f,b21=0.f;
        for (int d = t; d < DHEAD; d += NT) {
            float q0 = Wq[d], q1 = Wq[DHEAD + d];
            float k0 = Wk[d], k1 = Wk[DHEAD + d];
            float bb = bq[d];
            m00 += q0*k0; m01 += q0*k1; m10 += q1*k0; m11 += q1*k1;
            b20 += k0*bb; b21 += k1*bb;
        }
        red[t][0]=m00; red[t][1]=m01; red[t][2]=m10;
        red[t][3]=m11; red[t][4]=b20; red[t][5]=b21;
        __syncthreads();
        for (int s = NT/2; s > 0; s >>= 1) {
            if (t < s) {
                #pragma unroll
                for (int j = 0; j < 6; ++j) red[t][j] += red[t+s][j];
            }
            __syncthreads();
        }
        if (t < 6) ws[t] = red[0][t];
    } else {
        // absmax of x[b] for b = 2*(x-1), 2*(x-1)+1   (x = 1..8)
        __shared__ float red0[NT], red1[NT];
        #pragma unroll
        for (int j = 0; j < 2; ++j) {
            const int b = 2 * (blockIdx.x - 1) + j;
            const float* xb = x + (size_t)b * CLEN * 2;
            float m0 = 0.f, m1 = 0.f;
            for (int e = t; e < CLEN; e += NT) {
                float2 xe = *reinterpret_cast<const float2*>(xb + 2*e);
                m0 = fmaxf(m0, fabsf(xe.x));
                m1 = fmaxf(m1, fabsf(xe.y));
            }
            red0[t] = m0; red1[t] = m1;
            __syncthreads();
            for (int s = NT/2; s > 0; s >>= 1) {
                if (t < s) {
                    red0[t] = fmaxf(red0[t], red0[t+s]);
                    red1[t] = fmaxf(red1[t], red1[t+s]);
                }
                __syncthreads();
            }
            if (t == 0) { ws[WS_MX + 2*b] = red0[0]; ws[WS_MX + 2*b + 1] = red1[0]; }
            __syncthreads();
        }
    }
}

__device__ __forceinline__ float waveSum(float v) {
    #pragma unroll
    for (int off = 32; off > 0; off >>= 1) v += __shfl_xor(v, off);
    return v;
}

// ---- combo: blocks 0..7 finalize u (reduce partials + bo); blocks 8.. compute S ----
__launch_bounds__(NT, 4)
__global__ void ufinal_softmax(const float* __restrict__ bo, const float* __restrict__ x,
                               float* __restrict__ ws) {
    const int t = threadIdx.x;
    if (blockIdx.x < 8) {
        int o = blockIdx.x * NT + t;
        const float* part = ws + WS_PART;
        float u0=0.f, u1=0.f, w=0.f;
        #pragma unroll
        for (int y = 0; y < 64; ++y) {
            u0 += part[((size_t)y*3 + 0)*DHEAD + o];
            u1 += part[((size_t)y*3 + 1)*DHEAD + o];
            w  += part[((size_t)y*3 + 2)*DHEAD + o];
        }
        ws[WS_U0 + o] = u0;
        ws[WS_U1 + o] = u1;
        ws[WS_W  + o] = w + bo[o];
        return;
    }
    // ---- softmax coefficients, wave-autonomous (R9 structure, S to ws) ----
    const int lane = t & 63;
    const int wave = t >> 6;
    const int wid  = (blockIdx.x - 8) * 4 + wave;   // 0..SMWAVES-1

    const float M00 = ws[0], M01 = ws[1], M10 = ws[2], M11 = ws[3];
    const float B20 = ws[4], B21 = ws[5];
    float* S = ws + WS_S;

    #pragma unroll
    for (int i = 0; i < PPW; ++i) {
        const int p  = wid + i * SMWAVES;         // striped: balanced lengths
        const int b  = p & (BATCH - 1);
        const int q  = p >> 4;
        const int ca = 2 * q;
        const int na = ca + 1;                    // row a causal length
        const int nb = ca + 2;                    // row b causal length
        const float mx0 = ws[WS_MX + 2*b], mx1 = ws[WS_MX + 2*b + 1];
        const float* xb = x + (size_t)b * CLEN * 2;

        const float xa0 = xb[2*ca],     xa1 = xb[2*ca + 1];
        const float xb0 = xb[2*ca + 2], xb1 = xb[2*ca + 3];
        const float ga0 = M00*xa0 + M10*xa1 + B20;
        const float ga1 = M01*xa0 + M11*xa1 + B21;
        const float gb0 = M00*xb0 + M10*xb1 + B20;
        const float gb1 = M01*xb0 + M11*xb1 + B21;
        const float mua = fabsf(ga0)*mx0 + fabsf(ga1)*mx1;   // >= row-a max logit
        const float mub = fabsf(gb0)*mx0 + fabsf(gb1)*mx1;   // >= row-b max logit

        float psa=0.f, pa0=0.f, pa1=0.f, psb=0.f, pb0=0.f, pb1=0.f;
        const int iters = (nb + 127) >> 7;
        for (int it = 0; it < iters; ++it) {
            const int idx = 128*it + 2*lane;      // even element index
            f32x4 xe = *reinterpret_cast<const f32x4*>(xb + 2*idx);
            float l0a = ga0*xe.x + ga1*xe.y;
            float l1a = ga0*xe.z + ga1*xe.w;
            float l0b = gb0*xe.x + gb1*xe.y;
            float l1b = gb0*xe.z + gb1*xe.w;
            float e0a = (idx     < na) ? __expf(l0a - mua) : 0.f;
            float e1a = (idx + 1 < na) ? __expf(l1a - mua) : 0.f;
            float e0b = (idx     < nb) ? __expf(l0b - mub) : 0.f;
            float e1b = (idx + 1 < nb) ? __expf(l1b - mub) : 0.f;
            psa += e0a + e1a; pa0 += e0a*xe.x + e1a*xe.z; pa1 += e0a*xe.y + e1a*xe.w;
            psb += e0b + e1b; pb0 += e0b*xe.x + e1b*xe.z; pb1 += e0b*xe.y + e1b*xe.w;
        }
        psa = waveSum(psa); pa0 = waveSum(pa0); pa1 = waveSum(pa1);
        psb = waveSum(psb); pb0 = waveSum(pb0); pb1 = waveSum(pb1);
        if (lane == 0) {
            const int rowa = b * CLEN + ca;
            const float ia = 1.0f / psa, ib = 1.0f / psb;
            float2 sa = make_float2(pa0 * ia, pa1 * ia);
            float2 sb = make_float2(pb0 * ib, pb1 * ib);
            *reinterpret_cast<float2*>(S + 2*rowa)     = sa;
            *reinterpret_cast<float2*>(S + 2*rowa + 2) = sb;
        }
    }
}

// ---- sweep writer: fillBuffer clone. Block B owns half-row (r0 = B>>1,
// cols (B&1)*1024..), k-loop strides rows by 512 -> at step k the whole
// chip writes the contiguous 4MB window of rows [k*512,(k+1)*512).
// Per thread per step: one uniform 8B S load + 6 FMA + one dwordx4 store.
__launch_bounds__(NT, 4)
__global__ void write_sweep(const float* __restrict__ ws, float* __restrict__ out) {
    const int t  = threadIdx.x;
    const int B  = blockIdx.x;
    const int r0 = B >> 1;                    // 0..511
    const int c4 = ((B & 1) << 8) + t;        // quad column 0..511

    const f32x4* wsq = reinterpret_cast<const f32x4*>(ws);
    const f32x4 u0 = wsq[WS_U0/4 + c4];
    const f32x4 u1 = wsq[WS_U0/4 + 512 + c4];
    const f32x4 w  = wsq[WS_U0/4 + 1024 + c4];
    const float* S = ws + WS_S;
    f32x4* out4 = reinterpret_cast<f32x4*>(out);

    #pragma unroll 4
    for (int k = 0; k < SWK; ++k) {
        const int row = r0 + (k << 9);
        const float2 s = *reinterpret_cast<const float2*>(S + 2*row);
        f32x4 r;
        r.x = s.x*u0.x + s.y*u1.x + w.x;
        r.y = s.x*u0.y + s.y*u1.y + w.y;
        r.z = s.x*u0.z + s.y*u1.z + w.z;
        r.w = s.x*u0.w + s.y*u1.w + w.w;
        out4[(size_t)row * (DHEAD/4) + c4] = r;
    }
}

extern "C" void kernel_launch(void* const* d_in, const int* in_sizes, int n_in,
                              void* d_out, int out_size, void* d_ws, size_t ws_size,
                              hipStream_t stream) {
    const float* x  = (const float*)d_in[0];
    const float* Wk = (const float*)d_in[1];
    const float* bk = (const float*)d_in[2];  (void)bk; // cancels in softmax
    const float* Wq = (const float*)d_in[3];
    const float* bq = (const float*)d_in[4];
    const float* Wv = (const float*)d_in[5];
    const float* bv = (const float*)d_in[6];
    const float* Wo = (const float*)d_in[7];
    const float* bo = (const float*)d_in[8];
    float* out = (float*)d_out;
    float* ws  = (float*)d_ws;

    prep_u_partial<<<dim3(DHEAD / NT, 65), NT, 0, stream>>>(Wv, bv, Wo, Wq, Wk, bq, x, ws);
    ufinal_softmax<<<8 + SMBLK, NT, 0, stream>>>(bo, x, ws);
    write_sweep<<<SWGRID, NT, 0, stream>>>(ws, out);
}

// Round 12
// 66.074 us; speedup vs baseline: 1.6785x; 1.6785x over previous
//
#include <hip/hip_runtime.h>

#define BATCH   16
#define CLEN    2048
#define DHEAD   2048
#define NT      256
#define GRID    1024                 // 64 blocks per batch
#define NPAIR   (BATCH * CLEN / 2)   // 16384 row pairs; 16 per block, 4 per wave

typedef float f32x4 __attribute__((ext_vector_type(4)));

// ws layout (floats):
// [0..5]    : M00,M01,M10,M11,b2_0,b2_1
// [6..37]   : per-batch absmax mx[16][2]
// [40 ..]   : u0[2048], u1[2048], w[2048]
// [WS_PART] : prep partials [64 chunks][3][2048]
#define WS_MX   6
#define WS_U0   40
#define WS_U1   (40 + DHEAD)
#define WS_W    (40 + 2*DHEAD)
#define WS_PART (40 + 3*DHEAD)

// ---- prep B1 (+A fused): y<64: partial u chunks; y==64: M/b2 (x==0) or absmax (x>=1) ----
__global__ void prep_u_partial(const float* __restrict__ Wv, const float* __restrict__ bv,
                               const float* __restrict__ Wo, const float* __restrict__ Wq,
                               const float* __restrict__ Wk, const float* __restrict__ bq,
                               const float* __restrict__ x, float* __restrict__ ws) {
    const int t = threadIdx.x;
    if (blockIdx.y < 64) {
        int o  = blockIdx.x * NT + t;                // column of Wo, 0..2047
        int hb = blockIdx.y * 32;                    // 64 chunks of 32 rows
        float p0=0.f, p1=0.f, pw=0.f;
        #pragma unroll 4
        for (int h = hb; h < hb + 32; ++h) {
            float wo = Wo[(size_t)h * DHEAD + o];
            p0 += Wv[h]         * wo;
            p1 += Wv[DHEAD + h] * wo;
            pw += bv[h]         * wo;
        }
        float* part = ws + WS_PART;
        part[((size_t)blockIdx.y*3 + 0)*DHEAD + o] = p0;
        part[((size_t)blockIdx.y*3 + 1)*DHEAD + o] = p1;
        part[((size_t)blockIdx.y*3 + 2)*DHEAD + o] = pw;
    } else if (blockIdx.x == 0) {
        // M = Wq Wk^T (2x2), b2 = Wk @ bq
        __shared__ float red[NT][6];
        float m00=0.f,m01=0.f,m10=0.f,m11=0.f,b20=0.f,b21=0.f;
        for (int d = t; d < DHEAD; d += NT) {
            float q0 = Wq[d], q1 = Wq[DHEAD + d];
            float k0 = Wk[d], k1 = Wk[DHEAD + d];
            float bb = bq[d];
            m00 += q0*k0; m01 += q0*k1; m10 += q1*k0; m11 += q1*k1;
            b20 += k0*bb; b21 += k1*bb;
        }
        red[t][0]=m00; red[t][1]=m01; red[t][2]=m10;
        red[t][3]=m11; red[t][4]=b20; red[t][5]=b21;
        __syncthreads();
        for (int s = NT/2; s > 0; s >>= 1) {
            if (t < s) {
                #pragma unroll
                for (int j = 0; j < 6; ++j) red[t][j] += red[t+s][j];
            }
            __syncthreads();
        }
        if (t < 6) ws[t] = red[0][t];
    } else {
        // absmax of x[b] for b = 2*(x-1), 2*(x-1)+1   (x = 1..8)
        __shared__ float red0[NT], red1[NT];
        #pragma unroll
        for (int j = 0; j < 2; ++j) {
            const int b = 2 * (blockIdx.x - 1) + j;
            const float* xb = x + (size_t)b * CLEN * 2;
            float m0 = 0.f, m1 = 0.f;
            for (int e = t; e < CLEN; e += NT) {
                float2 xe = *reinterpret_cast<const float2*>(xb + 2*e);
                m0 = fmaxf(m0, fabsf(xe.x));
                m1 = fmaxf(m1, fabsf(xe.y));
            }
            red0[t] = m0; red1[t] = m1;
            __syncthreads();
            for (int s = NT/2; s > 0; s >>= 1) {
                if (t < s) {
                    red0[t] = fmaxf(red0[t], red0[t+s]);
                    red1[t] = fmaxf(red1[t], red1[t+s]);
                }
                __syncthreads();
            }
            if (t == 0) { ws[WS_MX + 2*b] = red0[0]; ws[WS_MX + 2*b + 1] = red1[0]; }
            __syncthreads();
        }
    }
}

// ---------------- prep B2: reduce partials, add bo ----------------
__global__ void prep_u_final(const float* __restrict__ bo, float* __restrict__ ws) {
    int o = blockIdx.x * NT + threadIdx.x;
    const float* part = ws + WS_PART;
    float u0=0.f, u1=0.f, w=0.f;
    #pragma unroll
    for (int y = 0; y < 64; ++y) {
        u0 += part[((size_t)y*3 + 0)*DHEAD + o];
        u1 += part[((size_t)y*3 + 1)*DHEAD + o];
        w  += part[((size_t)y*3 + 2)*DHEAD + o];
    }
    ws[WS_U0 + o] = u0;
    ws[WS_U1 + o] = u1;
    ws[WS_W  + o] = w + bo[o];
}

__device__ __forceinline__ float waveSum(float v) {
    #pragma unroll
    for (int off = 32; off > 0; off >>= 1) v += __shfl_xor(v, off);
    return v;
}

// ---------------- fused kernel with x in LDS: stores never wait ----------------
// Key mechanism: vmcnt is one in-order counter for global loads AND stores.
// By staging x[b] in LDS (16 KB, once per block), the steady-state pair loop
// uses only ds_read (lgkmcnt) + VALU + global stores (vmcnt). Nothing ever
// waits on vmcnt -> stores drain with pure backpressure, fillBuffer-like,
// while compute proceeds on the independent LDS counter. u stays in regs
// (R8's mistake was LDS on the per-store data path).
__launch_bounds__(NT, 3)
__global__ void attn_fused(const float* __restrict__ x, const float* __restrict__ ws,
                           float* __restrict__ out) {
    const int t    = threadIdx.x;
    const int lane = t & 63;
    const int wave = t >> 6;
    const int g    = blockIdx.x;
    const int b    = g >> 6;          // batch (uniform per block -> scalar loads)
    const int j    = g & 63;          // block index within batch

    __shared__ f32x4 sx[CLEN / 2];    // 16 KB: x[b] as 1024 f32x4 (2 rows each)

    // stage x[b] -> LDS, coalesced f32x4
    const f32x4* xq = reinterpret_cast<const f32x4*>(x + (size_t)b * CLEN * 2);
    #pragma unroll
    for (int i = 0; i < (CLEN/2) / NT; ++i)   // 4 iters
        sx[i * NT + t] = xq[i * NT + t];

    // u0/u1/w in registers (96 VGPRs), loads overlap staging
    f32x4 U0[8], U1[8], W[8];
    #pragma unroll
    for (int ch = 0; ch < 8; ++ch) {
        const int col = ch * 256 + 4 * lane;
        U0[ch] = *reinterpret_cast<const f32x4*>(ws + WS_U0 + col);
        U1[ch] = *reinterpret_cast<const f32x4*>(ws + WS_U1 + col);
        W[ch]  = *reinterpret_cast<const f32x4*>(ws + WS_W  + col);
    }
    const float M00 = ws[0], M01 = ws[1], M10 = ws[2], M11 = ws[3];
    const float B20 = ws[4], B21 = ws[5];
    const float mx0 = ws[WS_MX + 2*b], mx1 = ws[WS_MX + 2*b + 1];

    __syncthreads();                  // staging complete; the ONLY barrier

    #pragma unroll
    for (int i = 0; i < 4; ++i) {
        const int q  = j + 64 * (wave + 4 * i);   // 0..1023, striped lengths
        const int ca = 2 * q;
        const int na = ca + 1;                    // row a causal length
        const int nb = ca + 2;                    // row b causal length

        const f32x4 xh = sx[q];                   // {xa0,xa1,xb0,xb1} broadcast
        const float ga0 = M00*xh.x + M10*xh.y + B20;
        const float ga1 = M01*xh.x + M11*xh.y + B21;
        const float gb0 = M00*xh.z + M10*xh.w + B20;
        const float gb1 = M01*xh.z + M11*xh.w + B21;
        const float mua = fabsf(ga0)*mx0 + fabsf(ga1)*mx1;   // >= row-a max logit
        const float mub = fabsf(gb0)*mx0 + fabsf(gb1)*mx1;   // >= row-b max logit

        // one-pass softmax sums off LDS (lgkmcnt only — never waits on stores)
        float psa=0.f, pa0=0.f, pa1=0.f, psb=0.f, pb0=0.f, pb1=0.f;
        const int iters = (nb + 127) >> 7;
        for (int it = 0; it < iters; ++it) {
            const int idx = 128*it + 2*lane;      // even element index
            f32x4 xe = sx[64*it + lane];          // conflict-free b128 pattern
            float l0a = ga0*xe.x + ga1*xe.y;
            float l1a = ga0*xe.z + ga1*xe.w;
            float l0b = gb0*xe.x + gb1*xe.y;
            float l1b = gb0*xe.z + gb1*xe.w;
            float e0a = (idx     < na) ? __expf(l0a - mua) : 0.f;
            float e1a = (idx + 1 < na) ? __expf(l1a - mua) : 0.f;
            float e0b = (idx     < nb) ? __expf(l0b - mub) : 0.f;
            float e1b = (idx + 1 < nb) ? __expf(l1b - mub) : 0.f;
            psa += e0a + e1a; pa0 += e0a*xe.x + e1a*xe.z; pa1 += e0a*xe.y + e1a*xe.w;
            psb += e0b + e1b; pb0 += e0b*xe.x + e1b*xe.z; pb1 += e0b*xe.y + e1b*xe.w;
        }
        psa = waveSum(psa); pa0 = waveSum(pa0); pa1 = waveSum(pa1);
        psb = waveSum(psb); pb0 = waveSum(pb0); pb1 = waveSum(pb1);
        const float ia  = 1.0f / psa, ib = 1.0f / psb;
        const float S0a = pa0 * ia, S1a = pa1 * ia;
        const float S0b = pb0 * ib, S1b = pb1 * ib;

        // store burst: 2 rows x 8 x 1KB coalesced dwordx4, straight from regs
        float* orow = out + ((size_t)(b * CLEN + ca)) * DHEAD;
        #pragma unroll
        for (int ch = 0; ch < 8; ++ch) {
            const int col = ch * 256 + 4 * lane;
            f32x4 ra, rb;
            ra.x = S0a*U0[ch].x + S1a*U1[ch].x + W[ch].x;
            ra.y = S0a*U0[ch].y + S1a*U1[ch].y + W[ch].y;
            ra.z = S0a*U0[ch].z + S1a*U1[ch].z + W[ch].z;
            ra.w = S0a*U0[ch].w + S1a*U1[ch].w + W[ch].w;
            rb.x = S0b*U0[ch].x + S1b*U1[ch].x + W[ch].x;
            rb.y = S0b*U0[ch].y + S1b*U1[ch].y + W[ch].y;
            rb.z = S0b*U0[ch].z + S1b*U1[ch].z + W[ch].z;
            rb.w = S0b*U0[ch].w + S1b*U1[ch].w + W[ch].w;
            *reinterpret_cast<f32x4*>(orow + col)         = ra;
            *reinterpret_cast<f32x4*>(orow + DHEAD + col) = rb;
        }
    }
}

extern "C" void kernel_launch(void* const* d_in, const int* in_sizes, int n_in,
                              void* d_out, int out_size, void* d_ws, size_t ws_size,
                              hipStream_t stream) {
    const float* x  = (const float*)d_in[0];
    const float* Wk = (const float*)d_in[1];
    const float* bk = (const float*)d_in[2];  (void)bk; // cancels in softmax
    const float* Wq = (const float*)d_in[3];
    const float* bq = (const float*)d_in[4];
    const float* Wv = (const float*)d_in[5];
    const float* bv = (const float*)d_in[6];
    const float* Wo = (const float*)d_in[7];
    const float* bo = (const float*)d_in[8];
    float* out = (float*)d_out;
    float* ws  = (float*)d_ws;

    prep_u_partial<<<dim3(DHEAD / NT, 65), NT, 0, stream>>>(Wv, bv, Wo, Wq, Wk, bq, x, ws);
    prep_u_final<<<DHEAD / NT, NT, 0, stream>>>(bo, ws);
    attn_fused<<<GRID, NT, 0, stream>>>(x, ws, out);
}